// Round 7
// baseline (113.733 us; speedup 1.0000x reference)
//
#include <hip/hip_runtime.h>
#include <hip/hip_bf16.h>
#include <stdint.h>

typedef __bf16 bf16x8 __attribute__((ext_vector_type(8)));
typedef float  f32x4  __attribute__((ext_vector_type(4)));

#define B_   2
#define T_   2048
#define H_   16
#define DH_  64
#define DM_  1024
#define BH_  (B_*H_)   // 32
#define M_   (B_*T_)   // 4096

#define QSCALE 0.18033688f   // 1/sqrt(64) * log2(e), folded into Q
#define FIXED_M 8.0f         // static softmax max (exp2 domain)

// ---- async global->LDS, 16B per lane; LDS dest must be wave-uniform base ----
static __device__ __forceinline__ void gload_lds16(const void* g, void* lds) {
  __builtin_amdgcn_global_load_lds(
      (const __attribute__((address_space(1))) void*)(uintptr_t)g,
      (__attribute__((address_space(3))) void*)(uint32_t)(uintptr_t)lds,
      16, 0, 0);
}

// ---------------- conversion kernels ----------------
__global__ void k_cvt_bf16(const float* __restrict__ in, __hip_bfloat16* __restrict__ out, int n4) {
  int i = blockIdx.x * blockDim.x + threadIdx.x;
  if (i < n4) {
    float4 v = reinterpret_cast<const float4*>(in)[i];
    alignas(8) __hip_bfloat16 t[4] = {__float2bfloat16(v.x), __float2bfloat16(v.y),
                                      __float2bfloat16(v.z), __float2bfloat16(v.w)};
    reinterpret_cast<uint2*>(out)[i] = *reinterpret_cast<const uint2*>(t);
  }
}

// in [K][N] f32 row-major -> out [N][K] bf16 row-major (B^T for gemm_bt)
__global__ void k_cvtT(const float* __restrict__ in, __hip_bfloat16* __restrict__ out, int K, int N) {
  __shared__ float tile[32][33];
  int n0 = blockIdx.x * 32, k0 = blockIdx.y * 32;
  int tid = threadIdx.x;
  int kl = tid >> 3, n4 = (tid & 7) * 4;
  float4 v = *reinterpret_cast<const float4*>(in + (size_t)(k0 + kl) * N + n0 + n4);
  tile[kl][n4 + 0] = v.x; tile[kl][n4 + 1] = v.y; tile[kl][n4 + 2] = v.z; tile[kl][n4 + 3] = v.w;
  __syncthreads();
  int nl = tid >> 3, k4 = (tid & 7) * 4;
  alignas(8) __hip_bfloat16 t[4];
  #pragma unroll
  for (int j = 0; j < 4; ++j) t[j] = __float2bfloat16(tile[k4 + j][nl]);
  *reinterpret_cast<uint2*>(out + (size_t)(n0 + nl) * K + k0 + k4) = *reinterpret_cast<const uint2*>(t);
}

// ---------- templated bf16 GEMM core (B^T input), BK=32, 4 waves ----------
template<int BM, int BN, int FM, int FN>
static __device__ __forceinline__ void gemm_core(
    const __hip_bfloat16* __restrict__ A, const __hip_bfloat16* __restrict__ BT,
    int K, int brow, int bcol, __hip_bfloat16* As, __hip_bfloat16* Bs, f32x4 acc[FM][FN]) {
  constexpr int WGN = BN / (16 * FN);
  const int tid = threadIdx.x, wave = tid >> 6, lane = tid & 63;
  const int wr = wave / WGN, wc = wave % WGN;
  const int llo = lane & 15, lhi = lane >> 4;
  for (int k0 = 0; k0 < K; k0 += 32) {
    #pragma unroll
    for (int c = wave; c < BM / 16; c += 4)
      gload_lds16(A + (size_t)(brow + c * 16 + (lane >> 2)) * K + k0 + (lane & 3) * 8,
                  As + c * 16 * 32);
    #pragma unroll
    for (int c = wave; c < BN / 16; c += 4)
      gload_lds16(BT + (size_t)(bcol + c * 16 + (lane >> 2)) * K + k0 + (lane & 3) * 8,
                  Bs + c * 16 * 32);
    __syncthreads();
    bf16x8 a[FM], b[FN];
    #pragma unroll
    for (int i = 0; i < FM; ++i)
      a[i] = *reinterpret_cast<const bf16x8*>(As + (wr * FM * 16 + i * 16 + llo) * 32 + lhi * 8);
    #pragma unroll
    for (int j = 0; j < FN; ++j)
      b[j] = *reinterpret_cast<const bf16x8*>(Bs + (wc * FN * 16 + j * 16 + llo) * 32 + lhi * 8);
    #pragma unroll
    for (int i = 0; i < FM; ++i)
      #pragma unroll
      for (int j = 0; j < FN; ++j)
        acc[i][j] = __builtin_amdgcn_mfma_f32_16x16x32_bf16(a[i], b[j], acc[i][j], 0, 0, 0);
    __syncthreads();
  }
}

// GEMM1: qkv = xb @ w_qkv ; Q (pre-scaled) / K as [bh][t][dh]; V directly
// transposed to [bh][dh][t] (4 consecutive t per lane -> packed 8B store).
__global__ __launch_bounds__(256) void k_gemm_qkv(
    const __hip_bfloat16* __restrict__ A, const __hip_bfloat16* __restrict__ BT,
    __hip_bfloat16* __restrict__ q_ws, __hip_bfloat16* __restrict__ k_ws,
    __hip_bfloat16* __restrict__ vT) {
  alignas(16) __shared__ __hip_bfloat16 As[128 * 32];
  alignas(16) __shared__ __hip_bfloat16 Bs[128 * 32];
  f32x4 acc[4][4] = {};
  const int brow = blockIdx.y * 128, bcol = blockIdx.x * 128;
  gemm_core<128, 128, 4, 4>(A, BT, DM_, brow, bcol, As, Bs, acc);
  const int tid = threadIdx.x, wave = tid >> 6, lane = tid & 63;
  const int wr = wave >> 1, wc = wave & 1;
  const int llo = lane & 15, lhi = lane >> 4;
  #pragma unroll
  for (int i = 0; i < 4; ++i) {
    const int tbase = brow + wr * 64 + i * 16 + lhi * 4;  // 4 consecutive t
    const int b = tbase >> 11, t = tbase & 2047;
    #pragma unroll
    for (int j = 0; j < 4; ++j) {
      int n = bcol + wc * 64 + j * 16 + llo;
      int part = n >> 10, rem = n & 1023, hh = rem >> 6, dh = rem & 63;
      if (part == 2) {
        alignas(8) __hip_bfloat16 tv[4];
        #pragma unroll
        for (int r = 0; r < 4; ++r) tv[r] = __float2bfloat16(acc[i][j][r]);
        *reinterpret_cast<uint2*>(
            vT + (((size_t)(b * H_ + hh)) * DH_ + dh) * T_ + t) =
            *reinterpret_cast<const uint2*>(tv);
      } else {
        float sc = (part == 0) ? QSCALE : 1.0f;   // fold softmax scale into Q
        __hip_bfloat16* dst = (part == 0) ? q_ws : k_ws;
        #pragma unroll
        for (int r = 0; r < 4; ++r)
          dst[(((size_t)(b * H_ + hh)) * T_ + t + r) * DH_ + dh] =
              __float2bfloat16(acc[i][j][r] * sc);
      }
    }
  }
}

// GEMM2: out = y @ w_out (f32 output). 128x64 tile -> 512 blocks (2/CU).
__global__ __launch_bounds__(256) void k_gemm_out(
    const __hip_bfloat16* __restrict__ A, const __hip_bfloat16* __restrict__ BT,
    float* __restrict__ C) {
  alignas(16) __shared__ __hip_bfloat16 As[128 * 32];
  alignas(16) __shared__ __hip_bfloat16 Bs[64 * 32];
  f32x4 acc[4][2] = {};
  const int brow = blockIdx.y * 128, bcol = blockIdx.x * 64;
  gemm_core<128, 64, 4, 2>(A, BT, DM_, brow, bcol, As, Bs, acc);
  const int tid = threadIdx.x, wave = tid >> 6, lane = tid & 63;
  const int wr = wave >> 1, wc = wave & 1;
  const int llo = lane & 15, lhi = lane >> 4;
  #pragma unroll
  for (int i = 0; i < 4; ++i)
    #pragma unroll
    for (int j = 0; j < 2; ++j) {
      int n = bcol + wc * 32 + j * 16 + llo;
      #pragma unroll
      for (int r = 0; r < 4; ++r) {
        int m = brow + wr * 64 + i * 16 + lhi * 4 + r;
        C[(size_t)m * DM_ + n] = acc[i][j][r];
      }
    }
}

// ---------------- flash attention (causal), v7 ----------------
// Static-max softmax makes K-tile processing a pure commutative sum -> waves
// can split a q-tile's K-range. Group A (waves 0-3) owns qt=31-p, processes
// tiles 0..16 (always 17). Group B (waves 4-7) owns qt=p: own tiles 0..p,
// then HELPS A with tiles 31-p down to 17 (separate help accumulator, A's Q
// rows). Every block runs exactly 17 iterations -> zero wave idling, uniform
// CU makespan. Each group has its own 2-slot K/V sub-ring (stage-ahead-1,
// __syncthreads drain per iter). Epilogue: B writes o_help/l_help to LDS
// (reusing A's K slots), A combines before normalizing.
static __device__ __forceinline__ void attn_tile(
    const __hip_bfloat16* ksb, const __hip_bfloat16* vsb, __hip_bfloat16* PsW,
    const bf16x8* aq, int llo, int lhi, int qbase, int tile, bool do_mask,
    f32x4* o, float* lrow) {
  // S = Q K^T (K fragments from swizzled LDS; Q pre-scaled)
  f32x4 s[4];
  __builtin_amdgcn_s_setprio(1);
  #pragma unroll
  for (int jn = 0; jn < 4; ++jn) {
    const __hip_bfloat16* krow = ksb + (jn * 16 + llo) * 64;
    bf16x8 b0 = *reinterpret_cast<const bf16x8*>(krow + ((lhi ^ (llo & 7)) << 3));
    bf16x8 b1 = *reinterpret_cast<const bf16x8*>(krow + (((4 + lhi) ^ (llo & 7)) << 3));
    f32x4 z = {};
    z = __builtin_amdgcn_mfma_f32_16x16x32_bf16(aq[0], b0, z, 0, 0, 0);
    z = __builtin_amdgcn_mfma_f32_16x16x32_bf16(aq[1], b1, z, 0, 0, 0);
    s[jn] = z;
  }
  __builtin_amdgcn_s_setprio(0);
  if (do_mask) {
    #pragma unroll
    for (int jn = 0; jn < 4; ++jn)
      #pragma unroll
      for (int r = 0; r < 4; ++r) {
        int qrow = qbase + lhi * 4 + r;
        int tcol = tile * 64 + jn * 16 + llo;
        if (tcol > qrow) s[jn][r] = -INFINITY;
      }
  }
  // static-max softmax: p = exp2(s - FIXED_M); lane-local partial row sums
  #pragma unroll
  for (int jn = 0; jn < 4; ++jn)
    #pragma unroll
    for (int r = 0; r < 4; ++r) {
      float pv = __builtin_amdgcn_exp2f(s[jn][r] - FIXED_M);
      lrow[r] += pv;
      int row = lhi * 4 + r, col = jn * 16 + llo;
      PsW[row * 64 + (col ^ ((row & 7) << 3))] = __float2bfloat16(pv);
    }
  // PV
  bf16x8 ap0 = *reinterpret_cast<const bf16x8*>(&PsW[llo * 64 + ((lhi ^ (llo & 7)) << 3)]);
  bf16x8 ap1 = *reinterpret_cast<const bf16x8*>(&PsW[llo * 64 + (((4 + lhi) ^ (llo & 7)) << 3)]);
  __builtin_amdgcn_s_setprio(1);
  #pragma unroll
  for (int jd = 0; jd < 4; ++jd) {
    const __hip_bfloat16* vrow = vsb + (jd * 16 + llo) * 64;
    bf16x8 b0 = *reinterpret_cast<const bf16x8*>(vrow + ((lhi ^ (llo & 7)) << 3));
    bf16x8 b1 = *reinterpret_cast<const bf16x8*>(vrow + (((4 + lhi) ^ (llo & 7)) << 3));
    o[jd] = __builtin_amdgcn_mfma_f32_16x16x32_bf16(ap0, b0, o[jd], 0, 0, 0);
    o[jd] = __builtin_amdgcn_mfma_f32_16x16x32_bf16(ap1, b1, o[jd], 0, 0, 0);
  }
  __builtin_amdgcn_s_setprio(0);
}

__global__ __launch_bounds__(512, 4) void k_attn(
    const __hip_bfloat16* __restrict__ Q, const __hip_bfloat16* __restrict__ Kk,
    const __hip_bfloat16* __restrict__ VT, __hip_bfloat16* __restrict__ Y) {
  alignas(16) __shared__ __hip_bfloat16 Ks[4][64 * 64];  // slots: A=0,1  B=2,3
  alignas(16) __shared__ __hip_bfloat16 Vs[4][64 * 64];  // [dh][t'] swizzled
  alignas(16) __shared__ __hip_bfloat16 Ps[8][16 * 64];
  const int bh = blockIdx.y;
  const int p  = blockIdx.x;                 // 0..15
  const int tid = threadIdx.x, wave = tid >> 6, lane = tid & 63;
  const int llo = lane & 15, lhi = lane >> 4;
  const int group = wave >> 2, ws = wave & 3;
  const int qtA = 31 - p, qtB = p;
  const int qt_own = group ? qtB : qtA;
  const int qb_own  = qt_own * 64 + ws * 16;
  const int qb_help = qtA * 64 + ws * 16;    // B's help rows (A's q-tile)

  const __hip_bfloat16* kb = Kk + (size_t)bh * T_ * DH_;
  const __hip_bfloat16* vb = VT + (size_t)bh * DH_ * T_;

  // staging: group's 4 waves cover 64 rows; wave ws -> rows ws*16..+15
  // source chunk pre-swizzled so linear LDS write gives lds[row][chunk^(row&7)]
  const int srow = lane >> 3;                // 0..7
  const int schunk = (lane & 7) ^ srow;      // involution XOR
  const int rbase = ws * 16;

  // tile sequence for this group at iter j (-1 = none)
  auto seq = [&](int j) -> int {
    if (group == 0) return (j <= 16) ? j : -1;        // A: tiles 0..16
    if (j <= p) return j;                             // B own: 0..p
    if (j <= 15) return 32 - j;                       // B help: 31-p .. 17
    return -1;
  };
  auto stage = [&](int tile, int slot) {
    gload_lds16(kb + (size_t)(tile * 64 + rbase + srow) * DH_ + schunk * 8,
                &Ks[slot][rbase * 64]);
    gload_lds16(kb + (size_t)(tile * 64 + rbase + 8 + srow) * DH_ + schunk * 8,
                &Ks[slot][(rbase + 8) * 64]);
    gload_lds16(vb + (size_t)(rbase + srow) * T_ + tile * 64 + schunk * 8,
                &Vs[slot][rbase * 64]);
    gload_lds16(vb + (size_t)(rbase + 8 + srow) * T_ + tile * 64 + schunk * 8,
                &Vs[slot][(rbase + 8) * 64]);
  };

  bf16x8 aq_own[2], aq_help[2];
  #pragma unroll
  for (int k0 = 0; k0 < 2; ++k0) {
    aq_own[k0] = *reinterpret_cast<const bf16x8*>(
        Q + ((size_t)bh * T_ + qb_own + llo) * DH_ + k0 * 32 + lhi * 8);
    aq_help[k0] = *reinterpret_cast<const bf16x8*>(
        Q + ((size_t)bh * T_ + qb_help + llo) * DH_ + k0 * 32 + lhi * 8);
  }

  float l_own[4] = {0.f, 0.f, 0.f, 0.f}, l_help[4] = {0.f, 0.f, 0.f, 0.f};
  f32x4 o_own[4] = {}, o_help[4] = {};

  // prologue: stage seq(0)=0 into slot group*2
  stage(0, group * 2);
  __syncthreads();

  for (int j = 0; j <= 16; ++j) {
    // issue next tile's stage first (hides under compute; drain at barrier)
    const int s1 = seq(j + 1);
    if (s1 >= 0) stage(s1, group * 2 + ((j + 1) & 1));
    const int tc = seq(j);
    if (tc >= 0) {
      const __hip_bfloat16* ksb = &Ks[group * 2 + (j & 1)][0];
      const __hip_bfloat16* vsb = &Vs[group * 2 + (j & 1)][0];
      if (group == 0 || j <= p)
        attn_tile(ksb, vsb, &Ps[wave][0], aq_own, llo, lhi, qb_own, tc,
                  tc == qt_own, o_own, l_own);
      else
        attn_tile(ksb, vsb, &Ps[wave][0], aq_help, llo, lhi, qb_help, tc,
                  tc == qtA, o_help, l_help);
    }
    __syncthreads();   // drains stages (vmcnt0) + guards 2-slot ring reuse
  }

  // ---- combine: B's help accumulator -> A (via LDS, reusing A's K slots) ----
  float* Oh = reinterpret_cast<float*>(&Ks[0][0]);   // 16 KB (Ks slots 0-1)
  float* Lh = reinterpret_cast<float*>(&Vs[0][0]);   // 64 f32
  if (group == 1) {
    #pragma unroll
    for (int r = 0; r < 4; ++r) {
      float lh = l_help[r];
      #pragma unroll
      for (int d = 1; d < 16; d <<= 1) lh += __shfl_xor(lh, d);
      if (llo == 0) Lh[ws * 16 + lhi * 4 + r] = lh;
    }
    #pragma unroll
    for (int jd = 0; jd < 4; ++jd)
      #pragma unroll
      for (int r = 0; r < 4; ++r)
        Oh[ws * 1024 + (lhi * 4 + r) * 64 + jd * 16 + llo] = o_help[jd][r];
  }
  __syncthreads();

  float lr[4];
  #pragma unroll
  for (int r = 0; r < 4; ++r) {
    float ps = l_own[r];
    #pragma unroll
    for (int d = 1; d < 16; d <<= 1) ps += __shfl_xor(ps, d);
    lr[r] = ps;
  }
  if (group == 0) {
    #pragma unroll
    for (int r = 0; r < 4; ++r) lr[r] += Lh[ws * 16 + lhi * 4 + r];
    #pragma unroll
    for (int jd = 0; jd < 4; ++jd)
      #pragma unroll
      for (int r = 0; r < 4; ++r)
        o_own[jd][r] += Oh[ws * 1024 + (lhi * 4 + r) * 64 + jd * 16 + llo];
  }

  // epilogue: y[b][t][h*64+dh] for own q-rows
  const int b = bh >> 4, h = bh & 15;
  #pragma unroll
  for (int jd = 0; jd < 4; ++jd)
    #pragma unroll
    for (int r = 0; r < 4; ++r) {
      int trow = qb_own + lhi * 4 + r;
      int col = h * 64 + jd * 16 + llo;
      Y[((size_t)(b * T_ + trow)) * DM_ + col] = __float2bfloat16(o_own[jd][r] / lr[r]);
    }
}

// ---------------- launch ----------------
extern "C" void kernel_launch(void* const* d_in, const int* in_sizes, int n_in,
                              void* d_out, int out_size, void* d_ws, size_t ws_size,
                              hipStream_t stream) {
  const float* x     = (const float*)d_in[0];
  const float* w_qkv = (const float*)d_in[1];
  const float* w_out = (const float*)d_in[2];
  float* out = (float*)d_out;
  char* ws = (char*)d_ws;

  size_t off = 0;
  __hip_bfloat16* xb    = (__hip_bfloat16*)(ws + off); off += (size_t)M_ * DM_ * 2;      // 8 MiB
  __hip_bfloat16* wqkvT = (__hip_bfloat16*)(ws + off); off += (size_t)3 * DM_ * DM_ * 2; // 6 MiB
  __hip_bfloat16* woutT = (__hip_bfloat16*)(ws + off); off += (size_t)DM_ * DM_ * 2;     // 2 MiB
  __hip_bfloat16* q_ws  = (__hip_bfloat16*)(ws + off); off += (size_t)M_ * DM_ * 2;      // 8 MiB
  __hip_bfloat16* k_ws  = (__hip_bfloat16*)(ws + off); off += (size_t)M_ * DM_ * 2;      // 8 MiB
  __hip_bfloat16* vT    = (__hip_bfloat16*)(ws + off); off += (size_t)M_ * DM_ * 2;      // 8 MiB
  __hip_bfloat16* y_ws  = (__hip_bfloat16*)(ws + off); off += (size_t)M_ * DM_ * 2;      // 8 MiB
  (void)ws_size; (void)in_sizes; (void)n_in; (void)out_size;

  // convert inputs to bf16 (weights pre-transposed to B^T layout)
  k_cvt_bf16<<<(M_ * DM_ / 4 + 255) / 256, 256, 0, stream>>>(x, xb, M_ * DM_ / 4);
  k_cvtT<<<dim3(3 * DM_ / 32, DM_ / 32), 256, 0, stream>>>(w_qkv, wqkvT, DM_, 3 * DM_);
  k_cvtT<<<dim3(DM_ / 32, DM_ / 32), 256, 0, stream>>>(w_out, woutT, DM_, DM_);

  // qkv projection (Q pre-scaled; V written directly transposed)
  k_gemm_qkv<<<dim3(3 * DM_ / 128, M_ / 128), 256, 0, stream>>>(xb, wqkvT, q_ws, k_ws, vT);

  // causal flash attention (balanced dual-group help scheme)
  k_attn<<<dim3(T_ / 128, BH_), 512, 0, stream>>>(q_ws, k_ws, vT, y_ws);

  // output projection (f32 out), 128x64 tiles -> 512 blocks
  k_gemm_out<<<dim3(DM_ / 64, M_ / 128), 256, 0, stream>>>(y_ws, woutT, out);
}